// Round 21
// baseline (145.980 us; speedup 1.0000x reference)
//
#include <hip/hip_runtime.h>
#include <hip/hip_fp16.h>

static inline int cdiv(int a, int b) { return (a + b - 1) / b; }

#define BK_SHIFT 8     // 256 nodes per bucket
#define KBA_BLK 512    // builder blocks
#define PADB 4608      // padded slots per bucket (mean 4096, +8 sigma)

struct h2x4 { __half2 a, b, c, d; };  // 16 B = 8 halves

// ---------------- k_init: seed per-bucket global cursors ----------------
__global__ __launch_bounds__(512) void k_init(int* __restrict__ gcur, int nbuk) {
    int b = threadIdx.x;
    if (b < nbuk) gcur[b] = b * PADB;
}

// ---------------- kbA: single-pass bucketed pair build (hist -> reserve -> write) ----------------
__global__ __launch_bounds__(256) void kbA(const int* __restrict__ ei, int E, int epb, int nbuk,
                                           int* __restrict__ gcur,
                                           unsigned int* __restrict__ pairs) {
    __shared__ int h[512];
    __shared__ int lb[512];
    int blk = blockIdx.x;
    int beg = blk * epb, end = min(E, beg + epb);
    for (int b = threadIdx.x; b < nbuk; b += 256) h[b] = 0;
    __syncthreads();
    const int* dst = ei + E;
    for (int e = beg + threadIdx.x; e < end; e += 256)
        atomicAdd(&h[dst[e] >> BK_SHIFT], 1);
    __syncthreads();
    for (int b = threadIdx.x; b < nbuk; b += 256) {
        int c = h[b];
        lb[b] = c ? atomicAdd(&gcur[b], c) : 0;
    }
    __syncthreads();
    for (int e = beg + threadIdx.x; e < end; e += 256) {
        int d = dst[e];
        int s = ei[e];
        int slot = atomicAdd(&lb[d >> BK_SHIFT], 1);
        pairs[slot] = (unsigned)s | ((unsigned)(d & 255) << 17);
    }
}

// ---------------- k_sortcast: per-bucket counting sort + beg/end/dinv + fused x->xh cast ----------------
__global__ __launch_bounds__(1024) void k_sortcast(const unsigned int* __restrict__ pairs,
                                                   const int* __restrict__ gcur, int nbuk, int N,
                                                   const float* __restrict__ x,
                                                   int* __restrict__ csr_src,
                                                   int* __restrict__ begA, int* __restrict__ endA,
                                                   float* __restrict__ dinv,
                                                   __half* __restrict__ xh) {
    __shared__ int c[256];
    __shared__ int ex[256];
    __shared__ float sdi[256];
    __shared__ int sorted[PADB];
    int b = blockIdx.x;
    int tid = threadIdx.x;
    int base = b * PADB;
    int n = gcur[b] - base;
    if (tid < 256) c[tid] = 0;
    __syncthreads();
    int sr_[5], dl_[5], rk_[5];
#pragma unroll
    for (int k = 0; k < 5; ++k) {
        int i = tid + k * 1024;
        sr_[k] = -1;
        if (i < n) {
            unsigned int p = pairs[base + i];
            sr_[k] = (int)(p & 0x1FFFFu);
            dl_[k] = (int)(p >> 17);
            rk_[k] = atomicAdd(&c[dl_[k]], 1);
        }
    }
    __syncthreads();
    // exclusive scan of c[0..256) into ex: one wave, 4 entries/lane, shfl scan
    if (tid < 64) {
        int v0 = c[tid * 4 + 0], v1 = c[tid * 4 + 1], v2 = c[tid * 4 + 2], v3 = c[tid * 4 + 3];
        int s0 = v0, s1 = s0 + v1, s2 = s1 + v2, s3 = s2 + v3;
        int sum = s3;
#pragma unroll
        for (int off = 1; off < 64; off <<= 1) {
            int u = __shfl_up(sum, off);
            if (tid >= off) sum += u;
        }
        int excl = sum - s3;
        ex[tid * 4 + 0] = excl;
        ex[tid * 4 + 1] = excl + s0;
        ex[tid * 4 + 2] = excl + s1;
        ex[tid * 4 + 3] = excl + s2;
    }
    __syncthreads();
#pragma unroll
    for (int k = 0; k < 5; ++k) {
        if (sr_[k] >= 0) sorted[ex[dl_[k]] + rk_[k]] = sr_[k];
    }
    __syncthreads();
    for (int i = tid; i < n; i += 1024) csr_src[base + i] = sorted[i];
    if (tid < 256) {
        int g = (b << BK_SHIFT) + tid;
        if (g < N) {
            int bg = base + ex[tid];
            begA[g] = bg;
            endA[g] = bg + c[tid];
            float di = rsqrtf((float)(c[tid] + 1));  // +1 self loop
            dinv[g] = di;
            sdi[tid] = di;
        } else {
            sdi[tid] = 0.f;
        }
    }
    __syncthreads();
    // fused cast: this bucket's 256 nodes x 32 feats -> xh (pre-scaled by dinv)
    int g0 = b << BK_SHIFT;
    int nn = min(256, N - g0);
    const float4* x4 = (const float4*)x;  // 8 float4 per node
    for (int idx = tid; idx < nn * 8; idx += 1024) {
        int nd = idx >> 3;
        float di = sdi[nd];
        float4 v = x4[(size_t)(g0 + nd) * 8 + (idx & 7)];
        __half2 h0 = __floats2half2_rn(v.x * di, v.y * di);
        __half2 h1 = __floats2half2_rn(v.z * di, v.w * di);
        ((__half2*)xh)[2 * ((size_t)(g0 + nd) * 8 + (idx & 7))] = h0;
        ((__half2*)xh)[2 * ((size_t)(g0 + nd) * 8 + (idx & 7)) + 1] = h1;
    }
}

#define ACC8(W_) do { \
    float2 u_; \
    u_ = __half22float2((W_).a); acc[0] += u_.x; acc[1] += u_.y; \
    u_ = __half22float2((W_).b); acc[2] += u_.x; acc[3] += u_.y; \
    u_ = __half22float2((W_).c); acc[4] += u_.x; acc[5] += u_.y; \
    u_ = __half22float2((W_).d); acc[6] += u_.x; acc[7] += u_.y; \
} while (0)

// ---------------- fused layer 1: agg(F=32) + GEMM(32x64) + bias + relu + *dinv -> h2h ----------------
// 512 threads, 128 nodes/block; agg: 4 lanes/node (unroll 8); gemm: 32x16 threads, 4x4 tile.
__global__ __launch_bounds__(512) void k_fused1(const __half* __restrict__ feat,
                                                const int* __restrict__ begA,
                                                const int* __restrict__ endA,
                                                const int* __restrict__ csr_src,
                                                const float* __restrict__ dinv,
                                                const float* __restrict__ W,
                                                const float* __restrict__ b,
                                                __half* __restrict__ out, int N) {
    __shared__ float sX[128][33];
    __shared__ float sW[32][64];
    __shared__ float sDi[128];
    int tid = threadIdx.x;
    int g0 = blockIdx.x * 128;

    {
        const float4* Wv = (const float4*)W;
        float4* sWv = (float4*)&sW[0][0];
        sWv[tid] = Wv[tid];
    }
    {
        int gl = tid >> 2, q = tid & 3;
        int g = g0 + gl;
        const h2x4* f8 = (const h2x4*)feat;
        float acc[8] = {0.f, 0.f, 0.f, 0.f, 0.f, 0.f, 0.f, 0.f};
        float di = 0.f;
        if (g < N) {
            di = dinv[g];
            h2x4 w = f8[(size_t)g * 4 + q];  // self term (pre-scaled)
            ACC8(w);
            int beg = begA[g], end = endA[g];
            int e = beg;
            for (; e + 8 <= end; e += 8) {
                int s0 = csr_src[e + 0], s1 = csr_src[e + 1], s2 = csr_src[e + 2], s3 = csr_src[e + 3];
                int s4 = csr_src[e + 4], s5 = csr_src[e + 5], s6 = csr_src[e + 6], s7 = csr_src[e + 7];
                h2x4 w0 = f8[(size_t)s0 * 4 + q];
                h2x4 w1 = f8[(size_t)s1 * 4 + q];
                h2x4 w2 = f8[(size_t)s2 * 4 + q];
                h2x4 w3 = f8[(size_t)s3 * 4 + q];
                h2x4 w4 = f8[(size_t)s4 * 4 + q];
                h2x4 w5 = f8[(size_t)s5 * 4 + q];
                h2x4 w6 = f8[(size_t)s6 * 4 + q];
                h2x4 w7 = f8[(size_t)s7 * 4 + q];
                ACC8(w0); ACC8(w1); ACC8(w2); ACC8(w3);
                ACC8(w4); ACC8(w5); ACC8(w6); ACC8(w7);
            }
            for (; e < end; ++e) {
                h2x4 w4 = f8[(size_t)csr_src[e] * 4 + q];
                ACC8(w4);
            }
        }
        if (q == 0) sDi[gl] = di;
#pragma unroll
        for (int j = 0; j < 8; ++j) sX[gl][q * 8 + j] = acc[j] * di;
    }
    __syncthreads();
    int tm = tid & 31, tn = tid >> 5;
    float acc2[4][4];
    {
        float4 bb = *(const float4*)(b + tn * 4);
#pragma unroll
        for (int i = 0; i < 4; ++i) {
            acc2[i][0] = bb.x; acc2[i][1] = bb.y; acc2[i][2] = bb.z; acc2[i][3] = bb.w;
        }
    }
#pragma unroll 4
    for (int k = 0; k < 32; ++k) {
        float a0 = sX[tm * 4 + 0][k];
        float a1 = sX[tm * 4 + 1][k];
        float a2 = sX[tm * 4 + 2][k];
        float a3 = sX[tm * 4 + 3][k];
        float4 w = *(const float4*)&sW[k][tn * 4];
        float wv[4] = {w.x, w.y, w.z, w.w};
#pragma unroll
        for (int j = 0; j < 4; ++j) {
            acc2[0][j] = fmaf(a0, wv[j], acc2[0][j]);
            acc2[1][j] = fmaf(a1, wv[j], acc2[1][j]);
            acc2[2][j] = fmaf(a2, wv[j], acc2[2][j]);
            acc2[3][j] = fmaf(a3, wv[j], acc2[3][j]);
        }
    }
#pragma unroll
    for (int i = 0; i < 4; ++i) {
        int row = g0 + tm * 4 + i;
        if (row < N) {
            float di = sDi[tm * 4 + i];
            __half2 p0 = __floats2half2_rn(fmaxf(acc2[i][0], 0.f) * di, fmaxf(acc2[i][1], 0.f) * di);
            __half2 p1 = __floats2half2_rn(fmaxf(acc2[i][2], 0.f) * di, fmaxf(acc2[i][3], 0.f) * di);
            __half2* op = (__half2*)(out + (size_t)row * 64);
            op[tn * 2] = p0;
            op[tn * 2 + 1] = p1;
        }
    }
}

// ---------------- aggregation (layer 2): 8 features per lane, unroll 8 ----------------
__global__ __launch_bounds__(256) void k_agg64(const __half* __restrict__ feat,
                                               const int* __restrict__ begA,
                                               const int* __restrict__ endA,
                                               const int* __restrict__ csr_src,
                                               const float* __restrict__ dinv,
                                               float* __restrict__ out, int N) {
    constexpr int L = 8;
    int t = blockIdx.x * 256 + threadIdx.x;
    int g = t / L;
    int q = t % L;
    if (g >= N) return;
    const h2x4* f8 = (const h2x4*)feat;
    int beg = begA[g];
    int end = endA[g];
    float di = dinv[g];
    float acc[8];
    {
        h2x4 w = f8[(size_t)g * L + q];
        float2 p0 = __half22float2(w.a), p1 = __half22float2(w.b);
        float2 p2 = __half22float2(w.c), p3 = __half22float2(w.d);
        acc[0] = p0.x; acc[1] = p0.y; acc[2] = p1.x; acc[3] = p1.y;
        acc[4] = p2.x; acc[5] = p2.y; acc[6] = p3.x; acc[7] = p3.y;
    }
    int e = beg;
    for (; e + 8 <= end; e += 8) {
        int s0 = csr_src[e + 0], s1 = csr_src[e + 1], s2 = csr_src[e + 2], s3 = csr_src[e + 3];
        int s4 = csr_src[e + 4], s5 = csr_src[e + 5], s6 = csr_src[e + 6], s7 = csr_src[e + 7];
        h2x4 w0 = f8[(size_t)s0 * L + q];
        h2x4 w1 = f8[(size_t)s1 * L + q];
        h2x4 w2 = f8[(size_t)s2 * L + q];
        h2x4 w3 = f8[(size_t)s3 * L + q];
        h2x4 w4 = f8[(size_t)s4 * L + q];
        h2x4 w5 = f8[(size_t)s5 * L + q];
        h2x4 w6 = f8[(size_t)s6 * L + q];
        h2x4 w7 = f8[(size_t)s7 * L + q];
        ACC8(w0); ACC8(w1); ACC8(w2); ACC8(w3);
        ACC8(w4); ACC8(w5); ACC8(w6); ACC8(w7);
    }
    for (; e < end; ++e) {
        h2x4 w = f8[(size_t)csr_src[e] * L + q];
        ACC8(w);
    }
    float4 o0 = make_float4(acc[0] * di, acc[1] * di, acc[2] * di, acc[3] * di);
    float4 o1 = make_float4(acc[4] * di, acc[5] * di, acc[6] * di, acc[7] * di);
    ((float4*)out)[(size_t)g * 16 + q * 2] = o0;
    ((float4*)out)[(size_t)g * 16 + q * 2 + 1] = o1;
}

// ---------------- GEMM2: out = A[Nx64] @ W2[64x128] + b2 ----------------
__global__ __launch_bounds__(256) void k_gemm2(const float* __restrict__ A, const float* __restrict__ W,
                                               const float* __restrict__ b, float* __restrict__ out, int N) {
    __shared__ float sA[64][68];
    __shared__ float sW[64][128];
    int tid = threadIdx.x;
    int row0 = blockIdx.x * 64;

    {
        const float4* Wv = (const float4*)W;
        float4* sWv = (float4*)&sW[0][0];
#pragma unroll
        for (int i = 0; i < 8; ++i) sWv[tid + 256 * i] = Wv[tid + 256 * i];
    }
    {
        int row = tid >> 2;
        int gr = row0 + row;
        int kq = (tid & 3) * 4;
#pragma unroll
        for (int i = 0; i < 4; ++i) {
            int k0 = kq + 16 * i;
            float4 v = (gr < N) ? *(const float4*)(A + (size_t)gr * 64 + k0)
                                : make_float4(0.f, 0.f, 0.f, 0.f);
            sA[k0 + 0][row] = v.x;
            sA[k0 + 1][row] = v.y;
            sA[k0 + 2][row] = v.z;
            sA[k0 + 3][row] = v.w;
        }
    }
    __syncthreads();

    int tm = tid & 15, tn = tid >> 4;
    float acc[4][8];
    {
        float4 b0 = *(const float4*)(b + tn * 8);
        float4 b1 = *(const float4*)(b + tn * 8 + 4);
#pragma unroll
        for (int i = 0; i < 4; ++i) {
            acc[i][0] = b0.x; acc[i][1] = b0.y; acc[i][2] = b0.z; acc[i][3] = b0.w;
            acc[i][4] = b1.x; acc[i][5] = b1.y; acc[i][6] = b1.z; acc[i][7] = b1.w;
        }
    }
#pragma unroll 4
    for (int k = 0; k < 64; ++k) {
        float4 a = *(const float4*)&sA[k][tm * 4];
        float4 w0 = *(const float4*)&sW[k][tn * 8];
        float4 w1 = *(const float4*)&sW[k][tn * 8 + 4];
        float av[4] = {a.x, a.y, a.z, a.w};
        float wv[8] = {w0.x, w0.y, w0.z, w0.w, w1.x, w1.y, w1.z, w1.w};
#pragma unroll
        for (int i = 0; i < 4; ++i)
#pragma unroll
            for (int j = 0; j < 8; ++j) acc[i][j] = fmaf(av[i], wv[j], acc[i][j]);
    }
#pragma unroll
    for (int i = 0; i < 4; ++i) {
        int row = row0 + tm * 4 + i;
        if (row < N) {
            *(float4*)(out + (size_t)row * 128 + tn * 8) =
                make_float4(acc[i][0], acc[i][1], acc[i][2], acc[i][3]);
            *(float4*)(out + (size_t)row * 128 + tn * 8 + 4) =
                make_float4(acc[i][4], acc[i][5], acc[i][6], acc[i][7]);
        }
    }
}

extern "C" void kernel_launch(void* const* d_in, const int* in_sizes, int n_in,
                              void* d_out, int out_size, void* d_ws, size_t ws_size,
                              hipStream_t stream) {
    const float* x  = (const float*)d_in[0];
    const int*   ei = (const int*)d_in[1];
    const float* W1 = (const float*)d_in[2];
    const float* b1 = (const float*)d_in[3];
    const float* W2 = (const float*)d_in[4];
    const float* b2 = (const float*)d_in[5];
    float* out = (float*)d_out;

    const int N = in_sizes[0] / 32;
    const int E = in_sizes[1] / 2;
    const int epb = cdiv(E, KBA_BLK);
    const int nbuk = cdiv(N, 1 << BK_SHIFT);  // 391

    char* ws = (char*)d_ws;
    size_t off = 0;
    auto walloc = [&](size_t bytes) -> void* {
        void* p = ws + off;
        off = (off + bytes + 255) & ~(size_t)255;
        return p;
    };
    int*          gcur    = (int*)          walloc((size_t)(nbuk + 4) * 4);
    unsigned int* pairs   = (unsigned int*) walloc((size_t)nbuk * PADB * 4);  // 7.2 MB
    int*          csr_src = (int*)          walloc((size_t)nbuk * PADB * 4);  // 7.2 MB
    int*          begA    = (int*)          walloc((size_t)(N + 4) * 4);
    int*          endA    = (int*)          walloc((size_t)(N + 4) * 4);
    float*        dinv    = (float*)        walloc((size_t)N * 4);
    __half*       xh      = (__half*)       walloc((size_t)N * 32 * 2);       // 6.4 MB
    __half*       h2h     = (__half*)       walloc((size_t)N * 64 * 2);       // 12.8 MB
    float*        a2      = (float*)        walloc((size_t)N * 64 * 4);       // 25.6 MB
    (void)ws_size; (void)n_in; (void)out_size;

    k_init<<<1, 512, 0, stream>>>(gcur, nbuk);
    kbA<<<KBA_BLK, 256, 0, stream>>>(ei, E, epb, nbuk, gcur, pairs);
    k_sortcast<<<nbuk, 1024, 0, stream>>>(pairs, gcur, nbuk, N, x, csr_src, begA, endA, dinv, xh);

    k_fused1<<<cdiv(N, 128), 512, 0, stream>>>(xh, begA, endA, csr_src, dinv, W1, b1, h2h, N);

    k_agg64<<<cdiv(N * 8, 256), 256, 0, stream>>>(h2h, begA, endA, csr_src, dinv, a2, N);
    k_gemm2<<<cdiv(N, 64), 256, 0, stream>>>(a2, W2, b2, out, N);
}

// Round 22
// 138.469 us; speedup vs baseline: 1.0542x; 1.0542x over previous
//
#include <hip/hip_runtime.h>
#include <hip/hip_fp16.h>

static inline int cdiv(int a, int b) { return (a + b - 1) / b; }

#define BK_SHIFT 8     // 256 nodes per bucket
#define KBA_BLK 512    // builder blocks
#define PADB 4608      // padded slots per bucket (mean 4096, +8 sigma)

struct h2x4 { __half2 a, b, c, d; };  // 16 B = 8 halves

// ---------------- k_init: seed per-bucket global cursors ----------------
__global__ __launch_bounds__(512) void k_init(int* __restrict__ gcur, int nbuk) {
    int b = threadIdx.x;
    if (b < nbuk) gcur[b] = b * PADB;
}

// ---------------- kbA: single-pass bucketed pair build (hist -> reserve -> write) ----------------
__global__ __launch_bounds__(256) void kbA(const int* __restrict__ ei, int E, int epb, int nbuk,
                                           int* __restrict__ gcur,
                                           unsigned int* __restrict__ pairs) {
    __shared__ int h[512];
    __shared__ int lb[512];
    int blk = blockIdx.x;
    int beg = blk * epb, end = min(E, beg + epb);
    for (int b = threadIdx.x; b < nbuk; b += 256) h[b] = 0;
    __syncthreads();
    const int* dst = ei + E;
    for (int e = beg + threadIdx.x; e < end; e += 256)
        atomicAdd(&h[dst[e] >> BK_SHIFT], 1);
    __syncthreads();
    for (int b = threadIdx.x; b < nbuk; b += 256) {
        int c = h[b];
        lb[b] = c ? atomicAdd(&gcur[b], c) : 0;
    }
    __syncthreads();
    for (int e = beg + threadIdx.x; e < end; e += 256) {
        int d = dst[e];
        int s = ei[e];
        int slot = atomicAdd(&lb[d >> BK_SHIFT], 1);
        pairs[slot] = (unsigned)s | ((unsigned)(d & 255) << 17);
    }
}

// ---------------- k_sortcast: per-bucket counting sort + beg/end/dinv + fused x->xh cast ----------------
__global__ __launch_bounds__(1024) void k_sortcast(const unsigned int* __restrict__ pairs,
                                                   const int* __restrict__ gcur, int nbuk, int N,
                                                   const float* __restrict__ x,
                                                   int* __restrict__ csr_src,
                                                   int* __restrict__ begA, int* __restrict__ endA,
                                                   float* __restrict__ dinv,
                                                   __half* __restrict__ xh) {
    __shared__ int c[256];
    __shared__ int ex[256];
    __shared__ float sdi[256];
    __shared__ int sorted[PADB];
    int b = blockIdx.x;
    int tid = threadIdx.x;
    int base = b * PADB;
    int n = gcur[b] - base;
    if (tid < 256) c[tid] = 0;
    __syncthreads();
    int sr_[5], dl_[5], rk_[5];
#pragma unroll
    for (int k = 0; k < 5; ++k) {
        int i = tid + k * 1024;
        sr_[k] = -1;
        if (i < n) {
            unsigned int p = pairs[base + i];
            sr_[k] = (int)(p & 0x1FFFFu);
            dl_[k] = (int)(p >> 17);
            rk_[k] = atomicAdd(&c[dl_[k]], 1);
        }
    }
    __syncthreads();
    if (tid < 256) ex[tid] = c[tid];
    __syncthreads();
    for (int off = 1; off < 256; off <<= 1) {
        int u = (tid >= off && tid < 256) ? ex[tid - off] : 0;
        __syncthreads();
        if (tid < 256) ex[tid] += u;
        __syncthreads();
    }
    if (tid < 256) ex[tid] -= c[tid];  // exclusive
    __syncthreads();
#pragma unroll
    for (int k = 0; k < 5; ++k) {
        if (sr_[k] >= 0) sorted[ex[dl_[k]] + rk_[k]] = sr_[k];
    }
    __syncthreads();
    for (int i = tid; i < n; i += 1024) csr_src[base + i] = sorted[i];
    if (tid < 256) {
        int g = (b << BK_SHIFT) + tid;
        if (g < N) {
            int bg = base + ex[tid];
            begA[g] = bg;
            endA[g] = bg + c[tid];
            float di = rsqrtf((float)(c[tid] + 1));  // +1 self loop
            dinv[g] = di;
            sdi[tid] = di;
        } else {
            sdi[tid] = 0.f;
        }
    }
    __syncthreads();
    // fused cast: this bucket's 256 nodes x 32 feats -> xh (pre-scaled by dinv)
    int g0 = b << BK_SHIFT;
    int nn = min(256, N - g0);
    const float4* x4 = (const float4*)x;  // 8 float4 per node
    for (int idx = tid; idx < nn * 8; idx += 1024) {
        int nd = idx >> 3;
        float di = sdi[nd];
        float4 v = x4[(size_t)(g0 + nd) * 8 + (idx & 7)];
        __half2 h0 = __floats2half2_rn(v.x * di, v.y * di);
        __half2 h1 = __floats2half2_rn(v.z * di, v.w * di);
        ((__half2*)xh)[2 * ((size_t)(g0 + nd) * 8 + (idx & 7))] = h0;
        ((__half2*)xh)[2 * ((size_t)(g0 + nd) * 8 + (idx & 7)) + 1] = h1;
    }
}

// ---------------- fused layer 1: agg(F=32) + GEMM(32x64) + bias + relu + *dinv -> h2h ----------------
// 512 threads, 128 nodes/block; agg: 4 lanes/node; gemm: 32x16 threads, 4x4 tile.
__global__ __launch_bounds__(512) void k_fused1(const __half* __restrict__ feat,
                                                const int* __restrict__ begA,
                                                const int* __restrict__ endA,
                                                const int* __restrict__ csr_src,
                                                const float* __restrict__ dinv,
                                                const float* __restrict__ W,
                                                const float* __restrict__ b,
                                                __half* __restrict__ out, int N) {
    __shared__ float sX[128][33];
    __shared__ float sW[32][64];
    __shared__ float sDi[128];
    int tid = threadIdx.x;
    int g0 = blockIdx.x * 128;

    {
        const float4* Wv = (const float4*)W;
        float4* sWv = (float4*)&sW[0][0];
        sWv[tid] = Wv[tid];
    }
    {
        int gl = tid >> 2, q = tid & 3;
        int g = g0 + gl;
        const h2x4* f8 = (const h2x4*)feat;
        float acc[8] = {0.f, 0.f, 0.f, 0.f, 0.f, 0.f, 0.f, 0.f};
        float di = 0.f;
        if (g < N) {
            di = dinv[g];
            h2x4 w = f8[(size_t)g * 4 + q];  // self term (pre-scaled)
            float2 u;
            u = __half22float2(w.a); acc[0] = u.x; acc[1] = u.y;
            u = __half22float2(w.b); acc[2] = u.x; acc[3] = u.y;
            u = __half22float2(w.c); acc[4] = u.x; acc[5] = u.y;
            u = __half22float2(w.d); acc[6] = u.x; acc[7] = u.y;
            int beg = begA[g], end = endA[g];
            int e = beg;
            for (; e + 4 <= end; e += 4) {
                int s0 = csr_src[e + 0], s1 = csr_src[e + 1], s2 = csr_src[e + 2], s3 = csr_src[e + 3];
                h2x4 w0 = f8[(size_t)s0 * 4 + q];
                h2x4 w1 = f8[(size_t)s1 * 4 + q];
                h2x4 w2 = f8[(size_t)s2 * 4 + q];
                h2x4 w3 = f8[(size_t)s3 * 4 + q];
                u = __half22float2(w0.a); acc[0] += u.x; acc[1] += u.y;
                u = __half22float2(w0.b); acc[2] += u.x; acc[3] += u.y;
                u = __half22float2(w0.c); acc[4] += u.x; acc[5] += u.y;
                u = __half22float2(w0.d); acc[6] += u.x; acc[7] += u.y;
                u = __half22float2(w1.a); acc[0] += u.x; acc[1] += u.y;
                u = __half22float2(w1.b); acc[2] += u.x; acc[3] += u.y;
                u = __half22float2(w1.c); acc[4] += u.x; acc[5] += u.y;
                u = __half22float2(w1.d); acc[6] += u.x; acc[7] += u.y;
                u = __half22float2(w2.a); acc[0] += u.x; acc[1] += u.y;
                u = __half22float2(w2.b); acc[2] += u.x; acc[3] += u.y;
                u = __half22float2(w2.c); acc[4] += u.x; acc[5] += u.y;
                u = __half22float2(w2.d); acc[6] += u.x; acc[7] += u.y;
                u = __half22float2(w3.a); acc[0] += u.x; acc[1] += u.y;
                u = __half22float2(w3.b); acc[2] += u.x; acc[3] += u.y;
                u = __half22float2(w3.c); acc[4] += u.x; acc[5] += u.y;
                u = __half22float2(w3.d); acc[6] += u.x; acc[7] += u.y;
            }
            for (; e < end; ++e) {
                h2x4 w4 = f8[(size_t)csr_src[e] * 4 + q];
                u = __half22float2(w4.a); acc[0] += u.x; acc[1] += u.y;
                u = __half22float2(w4.b); acc[2] += u.x; acc[3] += u.y;
                u = __half22float2(w4.c); acc[4] += u.x; acc[5] += u.y;
                u = __half22float2(w4.d); acc[6] += u.x; acc[7] += u.y;
            }
        }
        if (q == 0) sDi[gl] = di;
#pragma unroll
        for (int j = 0; j < 8; ++j) sX[gl][q * 8 + j] = acc[j] * di;
    }
    __syncthreads();
    int tm = tid & 31, tn = tid >> 5;
    float acc2[4][4];
    {
        float4 bb = *(const float4*)(b + tn * 4);
#pragma unroll
        for (int i = 0; i < 4; ++i) {
            acc2[i][0] = bb.x; acc2[i][1] = bb.y; acc2[i][2] = bb.z; acc2[i][3] = bb.w;
        }
    }
#pragma unroll 4
    for (int k = 0; k < 32; ++k) {
        float a0 = sX[tm * 4 + 0][k];
        float a1 = sX[tm * 4 + 1][k];
        float a2 = sX[tm * 4 + 2][k];
        float a3 = sX[tm * 4 + 3][k];
        float4 w = *(const float4*)&sW[k][tn * 4];
        float wv[4] = {w.x, w.y, w.z, w.w};
#pragma unroll
        for (int j = 0; j < 4; ++j) {
            acc2[0][j] = fmaf(a0, wv[j], acc2[0][j]);
            acc2[1][j] = fmaf(a1, wv[j], acc2[1][j]);
            acc2[2][j] = fmaf(a2, wv[j], acc2[2][j]);
            acc2[3][j] = fmaf(a3, wv[j], acc2[3][j]);
        }
    }
#pragma unroll
    for (int i = 0; i < 4; ++i) {
        int row = g0 + tm * 4 + i;
        if (row < N) {
            float di = sDi[tm * 4 + i];
            __half2 p0 = __floats2half2_rn(fmaxf(acc2[i][0], 0.f) * di, fmaxf(acc2[i][1], 0.f) * di);
            __half2 p1 = __floats2half2_rn(fmaxf(acc2[i][2], 0.f) * di, fmaxf(acc2[i][3], 0.f) * di);
            __half2* op = (__half2*)(out + (size_t)row * 64);
            op[tn * 2] = p0;
            op[tn * 2 + 1] = p1;
        }
    }
}

// ---------------- aggregation (layer 2): 8 features per lane (16 B gathers) ----------------
__global__ __launch_bounds__(256) void k_agg64(const __half* __restrict__ feat,
                                               const int* __restrict__ begA,
                                               const int* __restrict__ endA,
                                               const int* __restrict__ csr_src,
                                               const float* __restrict__ dinv,
                                               float* __restrict__ out, int N) {
    constexpr int L = 8;
    int t = blockIdx.x * 256 + threadIdx.x;
    int g = t / L;
    int q = t % L;
    if (g >= N) return;
    const h2x4* f8 = (const h2x4*)feat;
    int beg = begA[g];
    int end = endA[g];
    float di = dinv[g];
    float acc[8];
    {
        h2x4 w = f8[(size_t)g * L + q];
        float2 p0 = __half22float2(w.a), p1 = __half22float2(w.b);
        float2 p2 = __half22float2(w.c), p3 = __half22float2(w.d);
        acc[0] = p0.x; acc[1] = p0.y; acc[2] = p1.x; acc[3] = p1.y;
        acc[4] = p2.x; acc[5] = p2.y; acc[6] = p3.x; acc[7] = p3.y;
    }
    int e = beg;
    for (; e + 4 <= end; e += 4) {
        int s0 = csr_src[e + 0], s1 = csr_src[e + 1], s2 = csr_src[e + 2], s3 = csr_src[e + 3];
        h2x4 w0 = f8[(size_t)s0 * L + q];
        h2x4 w1 = f8[(size_t)s1 * L + q];
        h2x4 w2 = f8[(size_t)s2 * L + q];
        h2x4 w3 = f8[(size_t)s3 * L + q];
        float2 u;
        u = __half22float2(w0.a); acc[0] += u.x; acc[1] += u.y;
        u = __half22float2(w0.b); acc[2] += u.x; acc[3] += u.y;
        u = __half22float2(w0.c); acc[4] += u.x; acc[5] += u.y;
        u = __half22float2(w0.d); acc[6] += u.x; acc[7] += u.y;
        u = __half22float2(w1.a); acc[0] += u.x; acc[1] += u.y;
        u = __half22float2(w1.b); acc[2] += u.x; acc[3] += u.y;
        u = __half22float2(w1.c); acc[4] += u.x; acc[5] += u.y;
        u = __half22float2(w1.d); acc[6] += u.x; acc[7] += u.y;
        u = __half22float2(w2.a); acc[0] += u.x; acc[1] += u.y;
        u = __half22float2(w2.b); acc[2] += u.x; acc[3] += u.y;
        u = __half22float2(w2.c); acc[4] += u.x; acc[5] += u.y;
        u = __half22float2(w2.d); acc[6] += u.x; acc[7] += u.y;
        u = __half22float2(w3.a); acc[0] += u.x; acc[1] += u.y;
        u = __half22float2(w3.b); acc[2] += u.x; acc[3] += u.y;
        u = __half22float2(w3.c); acc[4] += u.x; acc[5] += u.y;
        u = __half22float2(w3.d); acc[6] += u.x; acc[7] += u.y;
    }
    for (; e < end; ++e) {
        h2x4 w = f8[(size_t)csr_src[e] * L + q];
        float2 u;
        u = __half22float2(w.a); acc[0] += u.x; acc[1] += u.y;
        u = __half22float2(w.b); acc[2] += u.x; acc[3] += u.y;
        u = __half22float2(w.c); acc[4] += u.x; acc[5] += u.y;
        u = __half22float2(w.d); acc[6] += u.x; acc[7] += u.y;
    }
    float4 o0 = make_float4(acc[0] * di, acc[1] * di, acc[2] * di, acc[3] * di);
    float4 o1 = make_float4(acc[4] * di, acc[5] * di, acc[6] * di, acc[7] * di);
    ((float4*)out)[(size_t)g * 16 + q * 2] = o0;
    ((float4*)out)[(size_t)g * 16 + q * 2 + 1] = o1;
}

// ---------------- GEMM2: out = A[Nx64] @ W2[64x128] + b2 ----------------
__global__ __launch_bounds__(256) void k_gemm2(const float* __restrict__ A, const float* __restrict__ W,
                                               const float* __restrict__ b, float* __restrict__ out, int N) {
    __shared__ float sA[64][68];
    __shared__ float sW[64][128];
    int tid = threadIdx.x;
    int row0 = blockIdx.x * 64;

    {
        const float4* Wv = (const float4*)W;
        float4* sWv = (float4*)&sW[0][0];
#pragma unroll
        for (int i = 0; i < 8; ++i) sWv[tid + 256 * i] = Wv[tid + 256 * i];
    }
    {
        int row = tid >> 2;
        int gr = row0 + row;
        int kq = (tid & 3) * 4;
#pragma unroll
        for (int i = 0; i < 4; ++i) {
            int k0 = kq + 16 * i;
            float4 v = (gr < N) ? *(const float4*)(A + (size_t)gr * 64 + k0)
                                : make_float4(0.f, 0.f, 0.f, 0.f);
            sA[k0 + 0][row] = v.x;
            sA[k0 + 1][row] = v.y;
            sA[k0 + 2][row] = v.z;
            sA[k0 + 3][row] = v.w;
        }
    }
    __syncthreads();

    int tm = tid & 15, tn = tid >> 4;
    float acc[4][8];
    {
        float4 b0 = *(const float4*)(b + tn * 8);
        float4 b1 = *(const float4*)(b + tn * 8 + 4);
#pragma unroll
        for (int i = 0; i < 4; ++i) {
            acc[i][0] = b0.x; acc[i][1] = b0.y; acc[i][2] = b0.z; acc[i][3] = b0.w;
            acc[i][4] = b1.x; acc[i][5] = b1.y; acc[i][6] = b1.z; acc[i][7] = b1.w;
        }
    }
#pragma unroll 4
    for (int k = 0; k < 64; ++k) {
        float4 a = *(const float4*)&sA[k][tm * 4];
        float4 w0 = *(const float4*)&sW[k][tn * 8];
        float4 w1 = *(const float4*)&sW[k][tn * 8 + 4];
        float av[4] = {a.x, a.y, a.z, a.w};
        float wv[8] = {w0.x, w0.y, w0.z, w0.w, w1.x, w1.y, w1.z, w1.w};
#pragma unroll
        for (int i = 0; i < 4; ++i)
#pragma unroll
            for (int j = 0; j < 8; ++j) acc[i][j] = fmaf(av[i], wv[j], acc[i][j]);
    }
#pragma unroll
    for (int i = 0; i < 4; ++i) {
        int row = row0 + tm * 4 + i;
        if (row < N) {
            *(float4*)(out + (size_t)row * 128 + tn * 8) =
                make_float4(acc[i][0], acc[i][1], acc[i][2], acc[i][3]);
            *(float4*)(out + (size_t)row * 128 + tn * 8 + 4) =
                make_float4(acc[i][4], acc[i][5], acc[i][6], acc[i][7]);
        }
    }
}

extern "C" void kernel_launch(void* const* d_in, const int* in_sizes, int n_in,
                              void* d_out, int out_size, void* d_ws, size_t ws_size,
                              hipStream_t stream) {
    const float* x  = (const float*)d_in[0];
    const int*   ei = (const int*)d_in[1];
    const float* W1 = (const float*)d_in[2];
    const float* b1 = (const float*)d_in[3];
    const float* W2 = (const float*)d_in[4];
    const float* b2 = (const float*)d_in[5];
    float* out = (float*)d_out;

    const int N = in_sizes[0] / 32;
    const int E = in_sizes[1] / 2;
    const int epb = cdiv(E, KBA_BLK);
    const int nbuk = cdiv(N, 1 << BK_SHIFT);  // 391

    char* ws = (char*)d_ws;
    size_t off = 0;
    auto walloc = [&](size_t bytes) -> void* {
        void* p = ws + off;
        off = (off + bytes + 255) & ~(size_t)255;
        return p;
    };
    int*          gcur    = (int*)          walloc((size_t)(nbuk + 4) * 4);
    unsigned int* pairs   = (unsigned int*) walloc((size_t)nbuk * PADB * 4);  // 7.2 MB
    int*          csr_src = (int*)          walloc((size_t)nbuk * PADB * 4);  // 7.2 MB
    int*          begA    = (int*)          walloc((size_t)(N + 4) * 4);
    int*          endA    = (int*)          walloc((size_t)(N + 4) * 4);
    float*        dinv    = (float*)        walloc((size_t)N * 4);
    __half*       xh      = (__half*)       walloc((size_t)N * 32 * 2);       // 6.4 MB
    __half*       h2h     = (__half*)       walloc((size_t)N * 64 * 2);       // 12.8 MB
    float*        a2      = (float*)        walloc((size_t)N * 64 * 4);       // 25.6 MB
    (void)ws_size; (void)n_in; (void)out_size;

    k_init<<<1, 512, 0, stream>>>(gcur, nbuk);
    kbA<<<KBA_BLK, 256, 0, stream>>>(ei, E, epb, nbuk, gcur, pairs);
    k_sortcast<<<nbuk, 1024, 0, stream>>>(pairs, gcur, nbuk, N, x, csr_src, begA, endA, dinv, xh);

    k_fused1<<<cdiv(N, 128), 512, 0, stream>>>(xh, begA, endA, csr_src, dinv, W1, b1, h2h, N);

    k_agg64<<<cdiv(N * 8, 256), 256, 0, stream>>>(h2h, begA, endA, csr_src, dinv, a2, N);
    k_gemm2<<<cdiv(N, 64), 256, 0, stream>>>(a2, W2, b2, out, N);
}